// Round 1
// baseline (278.721 us; speedup 1.0000x reference)
//
#include <hip/hip_runtime.h>

// ---------------------------------------------------------------------------
// SelfMultiheadAttn fwd: T=2048, B=4, E=1024, H=16, D=64, causal.
// Round 9 = round 8 plus attn occupancy/VALU attack:
//  * attn grid 512 -> 1024 blocks (one q-tile per block, bh-major dispatch so
//    same-bh blocks stay concurrent for K/V L2 sharing; big qt first per bh).
//    LDS 48KB -> 3 blocks/CU resident (was capped at 2 by grid size).
//  * softmax scale folded into W_q during weight cvt (x 0.125*log2e, f32
//    precision) -> inner loop is a bare v_exp (exp2f), no per-element mul.
//  * diag/non-diag softmax paths split on wave-uniform flag -> mask
//    compare+cndmask only on the 2-of-~34 diagonal chunks.
// Round-7 lesson (kept): never feed MFMA from global, only stage via DMA.
// ---------------------------------------------------------------------------

typedef float  f32x4  __attribute__((ext_vector_type(4)));
typedef short  s16x8  __attribute__((ext_vector_type(8)));
typedef __bf16 bf16x8 __attribute__((ext_vector_type(8)));

#define T_DIM 2048
#define B_DIM 4
#define E_DIM 1024
#define PLANE (T_DIM * 64)   // elements per (which,b,h) plane

__device__ inline unsigned short f2bf(float f) {
  return (unsigned short)((__builtin_bit_cast(unsigned int, f) + 0x8000u) >> 16);
}

__device__ inline f32x4 mfma16(s16x8 a, s16x8 b, f32x4 c) {
  return __builtin_amdgcn_mfma_f32_16x16x32_bf16(
      __builtin_bit_cast(bf16x8, a), __builtin_bit_cast(bf16x8, b), c, 0, 0, 0);
}

__device__ inline void gl2lds16(const unsigned short* g, unsigned short* l) {
  __builtin_amdgcn_global_load_lds(
      (__attribute__((address_space(1))) unsigned int*)g,
      (__attribute__((address_space(3))) unsigned int*)l, 16, 0, 0);
}

// pack hi16(a) | hi16(b)<<16  (bf16 truncation) in one v_perm
__device__ inline unsigned packbf(float a, float b) {
  return __builtin_amdgcn_perm(__builtin_bit_cast(unsigned, b),
                               __builtin_bit_cast(unsigned, a), 0x07060302u);
}

// ---------------------------------------------------------------------------
__global__ __launch_bounds__(256)
void cvt_bf16(const float* __restrict__ in, unsigned short* __restrict__ out,
              int n4) {
  int i = blockIdx.x * 256 + threadIdx.x;
  if (i >= n4) return;
  float4 v = ((const float4*)in)[i];
  ushort4 o;
  o.x = f2bf(v.x); o.y = f2bf(v.y); o.z = f2bf(v.z); o.w = f2bf(v.w);
  ((ushort4*)out)[i] = o;
}

__global__ __launch_bounds__(256)
void cvt_bf16_scaled(const float* __restrict__ in,
                     unsigned short* __restrict__ out, int n4, float scale) {
  int i = blockIdx.x * 256 + threadIdx.x;
  if (i >= n4) return;
  float4 v = ((const float4*)in)[i];
  ushort4 o;
  o.x = f2bf(v.x * scale); o.y = f2bf(v.y * scale);
  o.z = f2bf(v.z * scale); o.w = f2bf(v.w * scale);
  ((ushort4*)out)[i] = o;
}

// ---------------------------------------------------------------------------
// gemm256: C[m,n]=sum_k A[m,k]*B[n,k]; 256x128 tile; both operands DMA-staged
// into swizzled LDS (single-buffered, m97 structure). Epilogue -> qkv scatter,
// V block via per-wave LDS transpose (reuses As).
// ---------------------------------------------------------------------------
__global__ __launch_bounds__(256, 2)
void gemm256(const unsigned short* __restrict__ A,
             const unsigned short* __restrict__ Bw,
             unsigned short* __restrict__ Cq, int K) {
  __shared__ __attribute__((aligned(16))) unsigned short As[256 * 64];
  __shared__ __attribute__((aligned(16))) unsigned short Bs[128 * 64];

  const int tid = threadIdx.x, lane = tid & 63, w = tid >> 6;
  const int row16 = lane & 15, quad = lane >> 4;
  const int m0 = blockIdx.y * 256, n0 = blockIdx.x * 128;
  const int wm = (w & 1) * 128, wn = (w >> 1) * 64;
  const int srow = lane >> 3;                  // 0..7 row within issue
  const int jsw = (lane & 7) ^ srow;           // swizzled 16B-chunk (staging)
  const int sw7 = row16 & 7;                   // read-side swizzle key

  f32x4 acc[8][4];
  for (int i = 0; i < 8; ++i)
    for (int j = 0; j < 4; ++j) acc[i][j] = (f32x4){0.f, 0.f, 0.f, 0.f};

  for (int k0 = 0; k0 < K; k0 += 64) {
    for (int i2 = 0; i2 < 8; ++i2) {          // A: 32 issues, 8 per wave
      int ia = w * 8 + i2;
      int r = ia * 8 + srow;
      gl2lds16(A + (size_t)(m0 + r) * K + k0 + jsw * 8, &As[ia * 512]);
    }
    for (int i2 = 0; i2 < 4; ++i2) {          // B: 16 issues, 4 per wave
      int ib = w * 4 + i2;
      int r = ib * 8 + srow;
      gl2lds16(Bw + (size_t)(n0 + r) * K + k0 + jsw * 8, &Bs[ib * 512]);
    }
    __syncthreads();
    for (int kk = 0; kk < 2; ++kk) {
      s16x8 af[8], bfr[4];
      for (int mi = 0; mi < 8; ++mi)
        af[mi] = *(const s16x8*)&As[(wm + mi * 16 + row16) * 64 +
                                    (((kk * 4 + quad) ^ sw7) * 8)];
      for (int ni = 0; ni < 4; ++ni)
        bfr[ni] = *(const s16x8*)&Bs[(wn + ni * 16 + row16) * 64 +
                                     (((kk * 4 + quad) ^ sw7) * 8)];
      for (int mi = 0; mi < 8; ++mi)
        for (int ni = 0; ni < 4; ++ni)
          acc[mi][ni] = mfma16(af[mi], bfr[ni], acc[mi][ni]);
    }
    __syncthreads();
  }

  if (n0 >= 2048) {
    // V block: per-wave transpose in LDS (As free after final barrier).
    // t = tg0 + mi*4+quad ; b = reg r ; dd = ni*16+row16 ; head hw.
    const int hw = ((n0 & 1023) >> 6) + (w >> 1);
    const int tg0 = (m0 >> 2) + (w & 1) * 32;
    unsigned short* tb = &As[w * 2560];        // 64 dd x 32 tl, stride 40
    for (int bb = 0; bb < 4; ++bb) {
      for (int mi = 0; mi < 8; ++mi)
        for (int ni = 0; ni < 4; ++ni)
          tb[(ni * 16 + row16) * 40 + mi * 4 + quad] = f2bf(acc[mi][ni][bb]);
      asm volatile("s_waitcnt lgkmcnt(0)" ::: "memory");
      unsigned short* vp = Cq + (size_t)(128 + bb * 16 + hw) * PLANE;
      for (int it = 0; it < 4; ++it) {
        int dd = it * 16 + (lane >> 2);
        int tl = (lane & 3) * 8;
        s16x8 v = *(const s16x8*)&tb[dd * 40 + tl];
        *(s16x8*)(vp + (size_t)dd * T_DIM + tg0 + tl) = v;
      }
      asm volatile("s_waitcnt lgkmcnt(0)" ::: "memory");  // WAR before next bb
    }
  } else {
    // Q/K blocks: [t][d] scatter (32B runs across row16 lanes)
    for (int mi = 0; mi < 8; ++mi)
      for (int ni = 0; ni < 4; ++ni)
        for (int r = 0; r < 4; ++r) {
          int m = m0 + wm + mi * 16 + quad * 4 + r;
          int n = n0 + wn + ni * 16 + row16;
          int t = m >> 2, bb = m & 3;
          int which = n >> 10, hh = (n >> 6) & 15, dd = n & 63;
          Cq[(size_t)(which * 64 + bb * 16 + hh) * PLANE + (size_t)t * 64 + dd] =
              f2bf(acc[mi][ni][r]);
        }
  }
}

// ---------------------------------------------------------------------------
// gemm128 (m97 structure, swizzled LDS), fp32 output — out-proj.
// ---------------------------------------------------------------------------
__global__ __launch_bounds__(256)
void gemm128(const unsigned short* __restrict__ A,
             const unsigned short* __restrict__ Bw,
             float* __restrict__ Cf, int N, int K) {
  __shared__ __attribute__((aligned(16))) unsigned short As[128 * 64];
  __shared__ __attribute__((aligned(16))) unsigned short Bs[128 * 64];

  const int tid = threadIdx.x, lane = tid & 63, w = tid >> 6;
  const int row16 = lane & 15, quad = lane >> 4;
  const int m0 = blockIdx.y * 128, n0 = blockIdx.x * 128;
  const int wm = (w & 1) * 64, wn = (w >> 1) * 64;
  const int srow = lane >> 3;
  const int jsw = (lane & 7) ^ srow;
  const int sw7 = row16 & 7;

  f32x4 acc[4][4];
  for (int i = 0; i < 4; ++i)
    for (int j = 0; j < 4; ++j) acc[i][j] = (f32x4){0.f, 0.f, 0.f, 0.f};

  for (int k0 = 0; k0 < K; k0 += 64) {
    for (int i = 0; i < 4; ++i) {
      int ia = i * 4 + w;
      int r = ia * 8 + srow;
      gl2lds16(A  + (size_t)(m0 + r) * K + k0 + jsw * 8, &As[ia * 512]);
      gl2lds16(Bw + (size_t)(n0 + r) * K + k0 + jsw * 8, &Bs[ia * 512]);
    }
    __syncthreads();
    for (int kk = 0; kk < 2; ++kk) {
      s16x8 af[4], bfr[4];
      for (int mi = 0; mi < 4; ++mi)
        af[mi] = *(const s16x8*)&As[(wm + mi * 16 + row16) * 64 +
                                    (((kk * 4 + quad) ^ sw7) * 8)];
      for (int ni = 0; ni < 4; ++ni)
        bfr[ni] = *(const s16x8*)&Bs[(wn + ni * 16 + row16) * 64 +
                                     (((kk * 4 + quad) ^ sw7) * 8)];
      for (int mi = 0; mi < 4; ++mi)
        for (int ni = 0; ni < 4; ++ni)
          acc[mi][ni] = mfma16(af[mi], bfr[ni], acc[mi][ni]);
    }
    __syncthreads();
  }

  for (int mi = 0; mi < 4; ++mi)
    for (int ni = 0; ni < 4; ++ni)
      for (int r = 0; r < 4; ++r) {
        int m = m0 + wm + mi * 16 + quad * 4 + r;
        int n = n0 + wn + ni * 16 + row16;
        Cf[(size_t)m * N + n] = acc[mi][ni][r];
      }
}

// ---------------------------------------------------------------------------
// Flash attention. grid = 1024 blocks, bh-major: block i -> bh = i>>4,
// qt = 15 - (i & 15)  (big q-tiles dispatched first within each bh so the
// 16 same-bh blocks run concurrently and share K/V through L2).
// One 128-row q-tile per block; K/Vt DMA double-buffered.
// W_q carries 0.125*log2e, so P = exp2(S) with no per-element scale mul.
// ---------------------------------------------------------------------------
__global__ __launch_bounds__(256)
void attn_fwd(const unsigned short* __restrict__ qkv,
              unsigned short* __restrict__ ctx) {
  __shared__ __attribute__((aligned(16))) unsigned short Ks[2][4096];
  __shared__ __attribute__((aligned(16))) unsigned short Vs[2][4096];
  __shared__ __attribute__((aligned(16))) unsigned short Ps[4][2048];

  const int tid = threadIdx.x, lane = tid & 63, w = tid >> 6;
  const int row16 = lane & 15, quad = lane >> 4;
  const int bh = blockIdx.x >> 4;
  const int qt = 15 - (blockIdx.x & 15);
  const int b = bh >> 4, h = bh & 15;

  const unsigned short* Qg = qkv + (size_t)bh * PLANE;          // [t][d]
  const unsigned short* Kg = qkv + (size_t)(64 + bh) * PLANE;   // [t][d]
  const unsigned short* Vt = qkv + (size_t)(128 + bh) * PLANE;  // [d][t]

  const int r8 = lane >> 3;
  const int jsw = (lane & 7) ^ r8;
  const int sw7 = row16 & 7;

  auto stage = [&](int c, int buf) {
    for (int i2 = 0; i2 < 2; ++i2) {
      int i = w + i2 * 4;
      int r = i * 8 + r8;
      gl2lds16(Kg + (size_t)(c * 64 + r) * 64 + jsw * 8, &Ks[buf][i * 512]);
      gl2lds16(Vt + (size_t)r * T_DIM + c * 64 + jsw * 8, &Vs[buf][i * 512]);
    }
  };

  const int q0w = qt * 128 + w * 32;
  const int cmax = 2 * qt + 1;
  const int dc = 2 * qt + (w >> 1);

  s16x8 qb[2][2];
  for (int nq = 0; nq < 2; ++nq)
    for (int s = 0; s < 2; ++s)
      qb[nq][s] = *(const s16x8*)(Qg + (size_t)(q0w + nq * 16 + row16) * 64 +
                                  s * 32 + quad * 8);

  f32x4 O[4][2];
  for (int md = 0; md < 4; ++md)
    for (int nq = 0; nq < 2; ++nq) O[md][nq] = (f32x4){0.f, 0.f, 0.f, 0.f};
  float lp[2] = {0.f, 0.f};

  stage(0, 0);
  __syncthreads();

  for (int c = 0; c <= cmax; ++c) {
    const int buf = c & 1;
    if (c < cmax) stage(c + 1, buf ^ 1);

    if (c <= dc) {
      f32x4 S[4][2];
      for (int nt = 0; nt < 4; ++nt)
        for (int nq = 0; nq < 2; ++nq) S[nt][nq] = (f32x4){0.f, 0.f, 0.f, 0.f};
      for (int nt = 0; nt < 4; ++nt)
        for (int s = 0; s < 2; ++s) {
          s16x8 ka = *(const s16x8*)&Ks[buf][(nt * 16 + row16) * 64 +
                                            (((s * 4 + quad) ^ sw7) * 8)];
          for (int nq = 0; nq < 2; ++nq)
            S[nt][nq] = mfma16(ka, qb[nq][s], S[nt][nq]);
        }

      // softmax numerator + pack into Ps; diag path carries the causal mask
      auto softmax_store = [&](bool diagm) {
        for (int nq = 0; nq < 2; ++nq) {
          const int qg = q0w + nq * 16 + row16;
          for (int nt = 0; nt < 4; ++nt) {
            float pv[4];
            for (int r = 0; r < 4; ++r) {
              pv[r] = __builtin_amdgcn_exp2f(S[nt][nq][r]);
              if (diagm && (c * 64 + nt * 16 + quad * 4 + r) > qg) pv[r] = 0.f;
              lp[nq] += pv[r];
            }
            int qr = nq * 16 + row16;
            int pos = (nt * 2 + (quad >> 1)) ^ sw7;
            *(uint2*)&Ps[w][qr * 64 + pos * 8 + (quad & 1) * 4] =
                make_uint2(packbf(pv[0], pv[1]), packbf(pv[2], pv[3]));
          }
        }
      };
      if (c == dc) softmax_store(true); else softmax_store(false);
      asm volatile("s_waitcnt lgkmcnt(0)" ::: "memory");

      for (int sk = 0; sk < 2; ++sk) {
        s16x8 pb[2];
        for (int nq = 0; nq < 2; ++nq)
          pb[nq] = *(const s16x8*)&Ps[w][(nq * 16 + row16) * 64 +
                                         (((sk * 4 + quad) ^ sw7) * 8)];
        for (int md = 0; md < 4; ++md) {
          s16x8 va = *(const s16x8*)&Vs[buf][(md * 16 + row16) * 64 +
                                            (((sk * 4 + quad) ^ sw7) * 8)];
          for (int nq = 0; nq < 2; ++nq)
            O[md][nq] = mfma16(va, pb[nq], O[md][nq]);
        }
      }
    }
    __syncthreads();
  }

  for (int nq = 0; nq < 2; ++nq) {
    float s = lp[nq];
    s += __shfl_xor(s, 16);
    s += __shfl_xor(s, 32);
    float inv = 1.f / s;
    const int t = q0w + nq * 16 + row16;
    for (int md = 0; md < 4; ++md) {
      unsigned lo = packbf(O[md][nq][0] * inv, O[md][nq][1] * inv);
      unsigned hi = packbf(O[md][nq][2] * inv, O[md][nq][3] * inv);
      *(uint2*)&ctx[((size_t)t * B_DIM + b) * E_DIM + h * 64 + md * 16 +
                    quad * 4] = make_uint2(lo, hi);
    }
  }
}

// ---------------------------------------------------------------------------
extern "C" void kernel_launch(void* const* d_in, const int* in_sizes, int n_in,
                              void* d_out, int out_size, void* d_ws,
                              size_t ws_size, hipStream_t stream) {
  const float* query = (const float*)d_in[0];  // [T,B,E] = [8192,1024]
  const float* win   = (const float*)d_in[1];  // [3072,1024]
  const float* wout  = (const float*)d_in[2];  // [1024,1024]
  float* out = (float*)d_out;

  unsigned short* qkvb = (unsigned short*)d_ws;          // 25,165,824 el
  unsigned short* ctxb = qkvb + (size_t)3 * B_DIM * 16 * T_DIM * 64;
  unsigned short* xb   = ctxb;                           // dies before ctx written
  unsigned short* winb = (unsigned short*)d_out;         // d_out scratch until gemm2
  unsigned short* woutb = qkvb;                          // qkv dead after attn

  // 0.125 (1/sqrt(D)) * log2(e): folded into W_q so attn uses exp2 directly.
  const float QSCALE = 0.18033688011112042f;

  cvt_bf16<<<8192, 256, 0, stream>>>(query, xb, (8192 * 1024) / 4);
  cvt_bf16_scaled<<<1024, 256, 0, stream>>>(win, winb, (1024 * 1024) / 4,
                                            QSCALE);
  cvt_bf16<<<2048, 256, 0, stream>>>(win + 1024 * 1024, winb + 1024 * 1024,
                                     (2048 * 1024) / 4);
  gemm256<<<dim3(3072 / 128, 8192 / 256), 256, 0, stream>>>(xb, winb, qkvb,
                                                            1024);
  attn_fwd<<<dim3(1024), 256, 0, stream>>>(qkvb, ctxb);
  cvt_bf16<<<1024, 256, 0, stream>>>(wout, woutb, (1024 * 1024) / 4);
  gemm128<<<dim3(8, 64), 256, 0, stream>>>(ctxb, woutb, out, 1024, 1024);
}

// Round 2
// 243.843 us; speedup vs baseline: 1.1430x; 1.1430x over previous
//
#include <hip/hip_runtime.h>

// ---------------------------------------------------------------------------
// SelfMultiheadAttn fwd: T=2048, B=4, E=1024, H=16, D=64, causal.
// Round 10:
//  * attn back to 512 UNIFORM blocks (pair qt=15-p then p; 34 iters each) —
//    round-9 lesson: non-uniform block work collapses time-avg occupancy.
//  * grid (64,8): linear id = p*64+bh -> same-bh blocks on same XCD (L2).
//  * K/V staging 4-deep (80KB LDS, 2 blocks/CU) with RAW s_barrier +
//    counted vmcnt(8/4/0) — removes the __syncthreads vmcnt(0) drain
//    (T3/T4). Prefetch stays 3 tiles in flight across barriers.
//  * s_setprio(1) around MFMA clusters (T5).
// Kept: exp2-folded W_q scale, diag/non-diag softmax split, DMA staging only
// (round-7 lesson: never feed MFMA from global).
// ---------------------------------------------------------------------------

typedef float  f32x4  __attribute__((ext_vector_type(4)));
typedef short  s16x8  __attribute__((ext_vector_type(8)));
typedef __bf16 bf16x8 __attribute__((ext_vector_type(8)));

#define T_DIM 2048
#define B_DIM 4
#define E_DIM 1024
#define PLANE (T_DIM * 64)   // elements per (which,b,h) plane

__device__ inline unsigned short f2bf(float f) {
  return (unsigned short)((__builtin_bit_cast(unsigned int, f) + 0x8000u) >> 16);
}

__device__ inline f32x4 mfma16(s16x8 a, s16x8 b, f32x4 c) {
  return __builtin_amdgcn_mfma_f32_16x16x32_bf16(
      __builtin_bit_cast(bf16x8, a), __builtin_bit_cast(bf16x8, b), c, 0, 0, 0);
}

__device__ inline void gl2lds16(const unsigned short* g, unsigned short* l) {
  __builtin_amdgcn_global_load_lds(
      (__attribute__((address_space(1))) unsigned int*)g,
      (__attribute__((address_space(3))) unsigned int*)l, 16, 0, 0);
}

// pack hi16(a) | hi16(b)<<16  (bf16 truncation) in one v_perm
__device__ inline unsigned packbf(float a, float b) {
  return __builtin_amdgcn_perm(__builtin_bit_cast(unsigned, b),
                               __builtin_bit_cast(unsigned, a), 0x07060302u);
}

// ---------------------------------------------------------------------------
__global__ __launch_bounds__(256)
void cvt_bf16(const float* __restrict__ in, unsigned short* __restrict__ out,
              int n4) {
  int i = blockIdx.x * 256 + threadIdx.x;
  if (i >= n4) return;
  float4 v = ((const float4*)in)[i];
  ushort4 o;
  o.x = f2bf(v.x); o.y = f2bf(v.y); o.z = f2bf(v.z); o.w = f2bf(v.w);
  ((ushort4*)out)[i] = o;
}

// in_proj weight cvt: first E rows (W_q) scaled by 0.125*log2e, rest as-is.
__global__ __launch_bounds__(256)
void cvt_w_in(const float* __restrict__ in, unsigned short* __restrict__ out,
              float qs) {
  int i = blockIdx.x * 256 + threadIdx.x;   // exactly 3072*1024/4 threads
  float sc = (i < (E_DIM * E_DIM / 4)) ? qs : 1.0f;
  float4 v = ((const float4*)in)[i];
  ushort4 o;
  o.x = f2bf(v.x * sc); o.y = f2bf(v.y * sc);
  o.z = f2bf(v.z * sc); o.w = f2bf(v.w * sc);
  ((ushort4*)out)[i] = o;
}

// ---------------------------------------------------------------------------
// gemm256: C[m,n]=sum_k A[m,k]*B[n,k]; 256x128 tile; both operands DMA-staged
// into swizzled LDS (single-buffered, m97 structure). Epilogue -> qkv scatter,
// V block via per-wave LDS transpose (reuses As).
// ---------------------------------------------------------------------------
__global__ __launch_bounds__(256, 2)
void gemm256(const unsigned short* __restrict__ A,
             const unsigned short* __restrict__ Bw,
             unsigned short* __restrict__ Cq, int K) {
  __shared__ __attribute__((aligned(16))) unsigned short As[256 * 64];
  __shared__ __attribute__((aligned(16))) unsigned short Bs[128 * 64];

  const int tid = threadIdx.x, lane = tid & 63, w = tid >> 6;
  const int row16 = lane & 15, quad = lane >> 4;
  const int m0 = blockIdx.y * 256, n0 = blockIdx.x * 128;
  const int wm = (w & 1) * 128, wn = (w >> 1) * 64;
  const int srow = lane >> 3;                  // 0..7 row within issue
  const int jsw = (lane & 7) ^ srow;           // swizzled 16B-chunk (staging)
  const int sw7 = row16 & 7;                   // read-side swizzle key

  f32x4 acc[8][4];
  for (int i = 0; i < 8; ++i)
    for (int j = 0; j < 4; ++j) acc[i][j] = (f32x4){0.f, 0.f, 0.f, 0.f};

  for (int k0 = 0; k0 < K; k0 += 64) {
    for (int i2 = 0; i2 < 8; ++i2) {          // A: 32 issues, 8 per wave
      int ia = w * 8 + i2;
      int r = ia * 8 + srow;
      gl2lds16(A + (size_t)(m0 + r) * K + k0 + jsw * 8, &As[ia * 512]);
    }
    for (int i2 = 0; i2 < 4; ++i2) {          // B: 16 issues, 4 per wave
      int ib = w * 4 + i2;
      int r = ib * 8 + srow;
      gl2lds16(Bw + (size_t)(n0 + r) * K + k0 + jsw * 8, &Bs[ib * 512]);
    }
    __syncthreads();
    for (int kk = 0; kk < 2; ++kk) {
      s16x8 af[8], bfr[4];
      for (int mi = 0; mi < 8; ++mi)
        af[mi] = *(const s16x8*)&As[(wm + mi * 16 + row16) * 64 +
                                    (((kk * 4 + quad) ^ sw7) * 8)];
      for (int ni = 0; ni < 4; ++ni)
        bfr[ni] = *(const s16x8*)&Bs[(wn + ni * 16 + row16) * 64 +
                                     (((kk * 4 + quad) ^ sw7) * 8)];
      for (int mi = 0; mi < 8; ++mi)
        for (int ni = 0; ni < 4; ++ni)
          acc[mi][ni] = mfma16(af[mi], bfr[ni], acc[mi][ni]);
    }
    __syncthreads();
  }

  if (n0 >= 2048) {
    // V block: per-wave transpose in LDS (As free after final barrier).
    // t = tg0 + mi*4+quad ; b = reg r ; dd = ni*16+row16 ; head hw.
    const int hw = ((n0 & 1023) >> 6) + (w >> 1);
    const int tg0 = (m0 >> 2) + (w & 1) * 32;
    unsigned short* tb = &As[w * 2560];        // 64 dd x 32 tl, stride 40
    for (int bb = 0; bb < 4; ++bb) {
      for (int mi = 0; mi < 8; ++mi)
        for (int ni = 0; ni < 4; ++ni)
          tb[(ni * 16 + row16) * 40 + mi * 4 + quad] = f2bf(acc[mi][ni][bb]);
      asm volatile("s_waitcnt lgkmcnt(0)" ::: "memory");
      unsigned short* vp = Cq + (size_t)(128 + bb * 16 + hw) * PLANE;
      for (int it = 0; it < 4; ++it) {
        int dd = it * 16 + (lane >> 2);
        int tl = (lane & 3) * 8;
        s16x8 v = *(const s16x8*)&tb[dd * 40 + tl];
        *(s16x8*)(vp + (size_t)dd * T_DIM + tg0 + tl) = v;
      }
      asm volatile("s_waitcnt lgkmcnt(0)" ::: "memory");  // WAR before next bb
    }
  } else {
    // Q/K blocks: [t][d] scatter (32B runs across row16 lanes)
    for (int mi = 0; mi < 8; ++mi)
      for (int ni = 0; ni < 4; ++ni)
        for (int r = 0; r < 4; ++r) {
          int m = m0 + wm + mi * 16 + quad * 4 + r;
          int n = n0 + wn + ni * 16 + row16;
          int t = m >> 2, bb = m & 3;
          int which = n >> 10, hh = (n >> 6) & 15, dd = n & 63;
          Cq[(size_t)(which * 64 + bb * 16 + hh) * PLANE + (size_t)t * 64 + dd] =
              f2bf(acc[mi][ni][r]);
        }
  }
}

// ---------------------------------------------------------------------------
// gemm128 (m97 structure, swizzled LDS), fp32 output — out-proj.
// ---------------------------------------------------------------------------
__global__ __launch_bounds__(256)
void gemm128(const unsigned short* __restrict__ A,
             const unsigned short* __restrict__ Bw,
             float* __restrict__ Cf, int N, int K) {
  __shared__ __attribute__((aligned(16))) unsigned short As[128 * 64];
  __shared__ __attribute__((aligned(16))) unsigned short Bs[128 * 64];

  const int tid = threadIdx.x, lane = tid & 63, w = tid >> 6;
  const int row16 = lane & 15, quad = lane >> 4;
  const int m0 = blockIdx.y * 128, n0 = blockIdx.x * 128;
  const int wm = (w & 1) * 64, wn = (w >> 1) * 64;
  const int srow = lane >> 3;
  const int jsw = (lane & 7) ^ srow;
  const int sw7 = row16 & 7;

  f32x4 acc[4][4];
  for (int i = 0; i < 4; ++i)
    for (int j = 0; j < 4; ++j) acc[i][j] = (f32x4){0.f, 0.f, 0.f, 0.f};

  for (int k0 = 0; k0 < K; k0 += 64) {
    for (int i = 0; i < 4; ++i) {
      int ia = i * 4 + w;
      int r = ia * 8 + srow;
      gl2lds16(A  + (size_t)(m0 + r) * K + k0 + jsw * 8, &As[ia * 512]);
      gl2lds16(Bw + (size_t)(n0 + r) * K + k0 + jsw * 8, &Bs[ia * 512]);
    }
    __syncthreads();
    for (int kk = 0; kk < 2; ++kk) {
      s16x8 af[4], bfr[4];
      for (int mi = 0; mi < 4; ++mi)
        af[mi] = *(const s16x8*)&As[(wm + mi * 16 + row16) * 64 +
                                    (((kk * 4 + quad) ^ sw7) * 8)];
      for (int ni = 0; ni < 4; ++ni)
        bfr[ni] = *(const s16x8*)&Bs[(wn + ni * 16 + row16) * 64 +
                                     (((kk * 4 + quad) ^ sw7) * 8)];
      for (int mi = 0; mi < 4; ++mi)
        for (int ni = 0; ni < 4; ++ni)
          acc[mi][ni] = mfma16(af[mi], bfr[ni], acc[mi][ni]);
    }
    __syncthreads();
  }

  for (int mi = 0; mi < 4; ++mi)
    for (int ni = 0; ni < 4; ++ni)
      for (int r = 0; r < 4; ++r) {
        int m = m0 + wm + mi * 16 + quad * 4 + r;
        int n = n0 + wn + ni * 16 + row16;
        Cf[(size_t)m * N + n] = acc[mi][ni][r];
      }
}

// ---------------------------------------------------------------------------
// Flash attention. grid = (64, 8): bh = blockIdx.x, p = blockIdx.y.
// Linear id = p*64+bh -> id%8 = bh%8: all 8 q-tile-blocks of a bh land on
// the same XCD (K/V L2 locality). Block handles q-tiles 15-p then p
// (uniform 34 chunk-iters). K/V staged 4-deep via DMA; raw s_barrier +
// counted vmcnt (no full drain — the round-8/9 kernels stalled ~900cy/iter
// on the __syncthreads vmcnt(0) drain of the just-issued prefetch).
// W_q carries 0.125*log2e, so P = exp2(S) with no per-element scale mul.
// ---------------------------------------------------------------------------
__global__ __launch_bounds__(256)
void attn_fwd(const unsigned short* __restrict__ qkv,
              unsigned short* __restrict__ ctx) {
  __shared__ __attribute__((aligned(16))) unsigned short Ks[4][4096];
  __shared__ __attribute__((aligned(16))) unsigned short Vs[4][4096];
  __shared__ __attribute__((aligned(16))) unsigned short Ps[4][2048];

  const int tid = threadIdx.x, lane = tid & 63, w = tid >> 6;
  const int row16 = lane & 15, quad = lane >> 4;
  const int bh = blockIdx.x;     // 0..63
  const int p  = blockIdx.y;     // 0..7
  const int b = bh >> 4, h = bh & 15;

  const unsigned short* Qg = qkv + (size_t)bh * PLANE;          // [t][d]
  const unsigned short* Kg = qkv + (size_t)(64 + bh) * PLANE;   // [t][d]
  const unsigned short* Vt = qkv + (size_t)(128 + bh) * PLANE;  // [d][t]

  const int r8 = lane >> 3;
  const int jsw = (lane & 7) ^ r8;
  const int sw7 = row16 & 7;

  auto stage = [&](int c, int buf) {   // 4 DMA loads per wave per call
    for (int i2 = 0; i2 < 2; ++i2) {
      int i = w + i2 * 4;
      int r = i * 8 + r8;
      gl2lds16(Kg + (size_t)(c * 64 + r) * 64 + jsw * 8, &Ks[buf][i * 512]);
      gl2lds16(Vt + (size_t)r * T_DIM + c * 64 + jsw * 8, &Vs[buf][i * 512]);
    }
  };

  for (int half = 0; half < 2; ++half) {
    const int qt = half ? p : (15 - p);
    const int q0w = qt * 128 + w * 32;
    const int cmax = 2 * qt + 1;           // >= 1 always
    const int dc = 2 * qt + (w >> 1);

    s16x8 qb[2][2];
    for (int nq = 0; nq < 2; ++nq)
      for (int s = 0; s < 2; ++s)
        qb[nq][s] = *(const s16x8*)(Qg + (size_t)(q0w + nq * 16 + row16) * 64 +
                                    s * 32 + quad * 8);

    f32x4 O[4][2];
    for (int md = 0; md < 4; ++md)
      for (int nq = 0; nq < 2; ++nq) O[md][nq] = (f32x4){0.f, 0.f, 0.f, 0.f};
    float lp[2] = {0.f, 0.f};

    // WAR: half-1 prologue overwrites buffers read at end of half-0.
    if (half) __builtin_amdgcn_s_barrier();
    stage(0, 0);
    stage(1, 1);
    if (cmax >= 2) stage(2, 2);

    for (int c = 0; c <= cmax; ++c) {
      const int buf = c & 3;
      const int rem = cmax - c;   // staged-ahead groups beyond c (max 2)
      // Counted wait: own group c landed; up to 2 newer groups stay in
      // flight across the barrier (T4 — never drain to 0 mid-loop).
      if (rem >= 2)      asm volatile("s_waitcnt vmcnt(8)" ::: "memory");
      else if (rem == 1) asm volatile("s_waitcnt vmcnt(4)" ::: "memory");
      else               asm volatile("s_waitcnt vmcnt(0)" ::: "memory");
      __builtin_amdgcn_s_barrier();  // all waves' group c landed; tile c-1 reads done
      if (c + 3 <= cmax) stage(c + 3, (c + 3) & 3);

      if (c <= dc) {
        f32x4 S[4][2];
        for (int nt = 0; nt < 4; ++nt)
          for (int nq = 0; nq < 2; ++nq) S[nt][nq] = (f32x4){0.f, 0.f, 0.f, 0.f};
        __builtin_amdgcn_s_setprio(1);
        for (int nt = 0; nt < 4; ++nt)
          for (int s = 0; s < 2; ++s) {
            s16x8 ka = *(const s16x8*)&Ks[buf][(nt * 16 + row16) * 64 +
                                              (((s * 4 + quad) ^ sw7) * 8)];
            for (int nq = 0; nq < 2; ++nq)
              S[nt][nq] = mfma16(ka, qb[nq][s], S[nt][nq]);
          }
        __builtin_amdgcn_s_setprio(0);

        // softmax numerator + pack into Ps; diag path carries the causal mask
        auto softmax_store = [&](bool diagm) {
          for (int nq = 0; nq < 2; ++nq) {
            const int qg = q0w + nq * 16 + row16;
            for (int nt = 0; nt < 4; ++nt) {
              float pv[4];
              for (int r = 0; r < 4; ++r) {
                pv[r] = __builtin_amdgcn_exp2f(S[nt][nq][r]);
                if (diagm && (c * 64 + nt * 16 + quad * 4 + r) > qg) pv[r] = 0.f;
                lp[nq] += pv[r];
              }
              int qr = nq * 16 + row16;
              int pos = (nt * 2 + (quad >> 1)) ^ sw7;
              *(uint2*)&Ps[w][qr * 64 + pos * 8 + (quad & 1) * 4] =
                  make_uint2(packbf(pv[0], pv[1]), packbf(pv[2], pv[3]));
            }
          }
        };
        if (c == dc) softmax_store(true); else softmax_store(false);
        asm volatile("s_waitcnt lgkmcnt(0)" ::: "memory");  // Ps is per-wave

        __builtin_amdgcn_s_setprio(1);
        for (int sk = 0; sk < 2; ++sk) {
          s16x8 pb[2];
          for (int nq = 0; nq < 2; ++nq)
            pb[nq] = *(const s16x8*)&Ps[w][(nq * 16 + row16) * 64 +
                                           (((sk * 4 + quad) ^ sw7) * 8)];
          for (int md = 0; md < 4; ++md) {
            s16x8 va = *(const s16x8*)&Vs[buf][(md * 16 + row16) * 64 +
                                              (((sk * 4 + quad) ^ sw7) * 8)];
            for (int nq = 0; nq < 2; ++nq)
              O[md][nq] = mfma16(va, pb[nq], O[md][nq]);
          }
        }
        __builtin_amdgcn_s_setprio(0);
      }
    }

    for (int nq = 0; nq < 2; ++nq) {
      float s = lp[nq];
      s += __shfl_xor(s, 16);
      s += __shfl_xor(s, 32);
      float inv = 1.f / s;
      const int t = q0w + nq * 16 + row16;
      for (int md = 0; md < 4; ++md) {
        unsigned lo = packbf(O[md][nq][0] * inv, O[md][nq][1] * inv);
        unsigned hi = packbf(O[md][nq][2] * inv, O[md][nq][3] * inv);
        *(uint2*)&ctx[((size_t)t * B_DIM + b) * E_DIM + h * 64 + md * 16 +
                      quad * 4] = make_uint2(lo, hi);
      }
    }
  }
}

// ---------------------------------------------------------------------------
extern "C" void kernel_launch(void* const* d_in, const int* in_sizes, int n_in,
                              void* d_out, int out_size, void* d_ws,
                              size_t ws_size, hipStream_t stream) {
  const float* query = (const float*)d_in[0];  // [T,B,E] = [8192,1024]
  const float* win   = (const float*)d_in[1];  // [3072,1024]
  const float* wout  = (const float*)d_in[2];  // [1024,1024]
  float* out = (float*)d_out;

  unsigned short* qkvb = (unsigned short*)d_ws;          // 25,165,824 el
  unsigned short* ctxb = qkvb + (size_t)3 * B_DIM * 16 * T_DIM * 64;
  unsigned short* xb   = ctxb;                           // dies before ctx written
  unsigned short* winb = (unsigned short*)d_out;         // d_out scratch until gemm2
  unsigned short* woutb = qkvb;                          // qkv dead after attn

  // 0.125 (1/sqrt(D)) * log2(e): folded into W_q so attn uses exp2 directly.
  const float QSCALE = 0.18033688011112042f;

  cvt_bf16<<<8192, 256, 0, stream>>>(query, xb, (8192 * 1024) / 4);
  cvt_w_in<<<3072, 256, 0, stream>>>(win, winb, QSCALE);
  gemm256<<<dim3(3072 / 128, 8192 / 256), 256, 0, stream>>>(xb, winb, qkvb,
                                                            1024);
  attn_fwd<<<dim3(64, 8), 256, 0, stream>>>(qkvb, ctxb);
  cvt_bf16<<<1024, 256, 0, stream>>>(wout, woutb, (1024 * 1024) / 4);
  gemm128<<<dim3(8, 64), 256, 0, stream>>>(ctxb, woutb, out, 1024, 1024);
}

// Round 3
// 232.525 us; speedup vs baseline: 1.1987x; 1.0487x over previous
//
#include <hip/hip_runtime.h>

// ---------------------------------------------------------------------------
// SelfMultiheadAttn fwd: T=2048, B=4, E=1024, H=16, D=64, causal.
// Round 11:
//  * attn LDS 80KB -> 48KB: K/V staging 2-deep (was 4-deep) -> 3 blocks/CU
//    (round-10 showed the loop is latency-bound at 2 waves/SIMD; trade
//    pipeline depth for resident waves). Counted vmcnt kept: vmcnt(4)
//    mid-loop, vmcnt(0) only at the final iter. 2-deep WAR needs a second
//    barrier per iter (after compute, before re-staging the read buffer).
//  * one merged cvt kernel for query/W_in/W_out (saves 2 launch gaps);
//    W_out bf16 goes to fresh ws after ctx when ws_size allows, else the
//    old post-attn qkvb reuse.
// Kept from round 10 (verified +32 µs): uniform (15-p, p) pairing,
// (64,8) grid -> same-bh blocks on same XCD (FETCH 110->30 MB), exp2-folded
// W_q scale, diag/non-diag softmax split, setprio around MFMA, DMA-only
// staging (round-7 lesson: never feed MFMA from global).
// ---------------------------------------------------------------------------

typedef float  f32x4  __attribute__((ext_vector_type(4)));
typedef short  s16x8  __attribute__((ext_vector_type(8)));
typedef __bf16 bf16x8 __attribute__((ext_vector_type(8)));

#define T_DIM 2048
#define B_DIM 4
#define E_DIM 1024
#define PLANE (T_DIM * 64)   // elements per (which,b,h) plane

__device__ inline unsigned short f2bf(float f) {
  return (unsigned short)((__builtin_bit_cast(unsigned int, f) + 0x8000u) >> 16);
}

__device__ inline f32x4 mfma16(s16x8 a, s16x8 b, f32x4 c) {
  return __builtin_amdgcn_mfma_f32_16x16x32_bf16(
      __builtin_bit_cast(bf16x8, a), __builtin_bit_cast(bf16x8, b), c, 0, 0, 0);
}

__device__ inline void gl2lds16(const unsigned short* g, unsigned short* l) {
  __builtin_amdgcn_global_load_lds(
      (__attribute__((address_space(1))) unsigned int*)g,
      (__attribute__((address_space(3))) unsigned int*)l, 16, 0, 0);
}

// pack hi16(a) | hi16(b)<<16  (bf16 truncation) in one v_perm
__device__ inline unsigned packbf(float a, float b) {
  return __builtin_amdgcn_perm(__builtin_bit_cast(unsigned, b),
                               __builtin_bit_cast(unsigned, a), 0x07060302u);
}

// ---------------------------------------------------------------------------
// Merged input conversion: blocks [0,8192) query -> xb; [8192,11264) W_in ->
// winb (first E*E/4 float4s carry the Q scale); [11264,12288) W_out -> wob
// (skipped when do_wout==0; fallback path converts W_out after attn).
// ---------------------------------------------------------------------------
__global__ __launch_bounds__(256)
void cvt_all(const float* __restrict__ q, const float* __restrict__ wi,
             const float* __restrict__ wo, unsigned short* __restrict__ xb,
             unsigned short* __restrict__ wib, unsigned short* __restrict__ wob,
             float qs, int do_wout) {
  int blk = blockIdx.x;
  const float* src;
  unsigned short* dst;
  int i;
  float sc = 1.0f;
  if (blk < 8192) {
    src = q; dst = xb; i = blk * 256 + threadIdx.x;
  } else if (blk < 11264) {
    src = wi; dst = wib; i = (blk - 8192) * 256 + threadIdx.x;
    if (i < (E_DIM * E_DIM / 4)) sc = qs;
  } else {
    if (!do_wout) return;
    src = wo; dst = wob; i = (blk - 11264) * 256 + threadIdx.x;
  }
  float4 v = ((const float4*)src)[i];
  ushort4 o;
  o.x = f2bf(v.x * sc); o.y = f2bf(v.y * sc);
  o.z = f2bf(v.z * sc); o.w = f2bf(v.w * sc);
  ((ushort4*)dst)[i] = o;
}

__global__ __launch_bounds__(256)
void cvt_bf16(const float* __restrict__ in, unsigned short* __restrict__ out,
              int n4) {
  int i = blockIdx.x * 256 + threadIdx.x;
  if (i >= n4) return;
  float4 v = ((const float4*)in)[i];
  ushort4 o;
  o.x = f2bf(v.x); o.y = f2bf(v.y); o.z = f2bf(v.z); o.w = f2bf(v.w);
  ((ushort4*)out)[i] = o;
}

// ---------------------------------------------------------------------------
// gemm256: C[m,n]=sum_k A[m,k]*B[n,k]; 256x128 tile; both operands DMA-staged
// into swizzled LDS (single-buffered, m97 structure). Epilogue -> qkv scatter,
// V block via per-wave LDS transpose (reuses As).
// ---------------------------------------------------------------------------
__global__ __launch_bounds__(256, 2)
void gemm256(const unsigned short* __restrict__ A,
             const unsigned short* __restrict__ Bw,
             unsigned short* __restrict__ Cq, int K) {
  __shared__ __attribute__((aligned(16))) unsigned short As[256 * 64];
  __shared__ __attribute__((aligned(16))) unsigned short Bs[128 * 64];

  const int tid = threadIdx.x, lane = tid & 63, w = tid >> 6;
  const int row16 = lane & 15, quad = lane >> 4;
  const int m0 = blockIdx.y * 256, n0 = blockIdx.x * 128;
  const int wm = (w & 1) * 128, wn = (w >> 1) * 64;
  const int srow = lane >> 3;                  // 0..7 row within issue
  const int jsw = (lane & 7) ^ srow;           // swizzled 16B-chunk (staging)
  const int sw7 = row16 & 7;                   // read-side swizzle key

  f32x4 acc[8][4];
  for (int i = 0; i < 8; ++i)
    for (int j = 0; j < 4; ++j) acc[i][j] = (f32x4){0.f, 0.f, 0.f, 0.f};

  for (int k0 = 0; k0 < K; k0 += 64) {
    for (int i2 = 0; i2 < 8; ++i2) {          // A: 32 issues, 8 per wave
      int ia = w * 8 + i2;
      int r = ia * 8 + srow;
      gl2lds16(A + (size_t)(m0 + r) * K + k0 + jsw * 8, &As[ia * 512]);
    }
    for (int i2 = 0; i2 < 4; ++i2) {          // B: 16 issues, 4 per wave
      int ib = w * 4 + i2;
      int r = ib * 8 + srow;
      gl2lds16(Bw + (size_t)(n0 + r) * K + k0 + jsw * 8, &Bs[ib * 512]);
    }
    __syncthreads();
    for (int kk = 0; kk < 2; ++kk) {
      s16x8 af[8], bfr[4];
      for (int mi = 0; mi < 8; ++mi)
        af[mi] = *(const s16x8*)&As[(wm + mi * 16 + row16) * 64 +
                                    (((kk * 4 + quad) ^ sw7) * 8)];
      for (int ni = 0; ni < 4; ++ni)
        bfr[ni] = *(const s16x8*)&Bs[(wn + ni * 16 + row16) * 64 +
                                     (((kk * 4 + quad) ^ sw7) * 8)];
      for (int mi = 0; mi < 8; ++mi)
        for (int ni = 0; ni < 4; ++ni)
          acc[mi][ni] = mfma16(af[mi], bfr[ni], acc[mi][ni]);
    }
    __syncthreads();
  }

  if (n0 >= 2048) {
    // V block: per-wave transpose in LDS (As free after final barrier).
    // t = tg0 + mi*4+quad ; b = reg r ; dd = ni*16+row16 ; head hw.
    const int hw = ((n0 & 1023) >> 6) + (w >> 1);
    const int tg0 = (m0 >> 2) + (w & 1) * 32;
    unsigned short* tb = &As[w * 2560];        // 64 dd x 32 tl, stride 40
    for (int bb = 0; bb < 4; ++bb) {
      for (int mi = 0; mi < 8; ++mi)
        for (int ni = 0; ni < 4; ++ni)
          tb[(ni * 16 + row16) * 40 + mi * 4 + quad] = f2bf(acc[mi][ni][bb]);
      asm volatile("s_waitcnt lgkmcnt(0)" ::: "memory");
      unsigned short* vp = Cq + (size_t)(128 + bb * 16 + hw) * PLANE;
      for (int it = 0; it < 4; ++it) {
        int dd = it * 16 + (lane >> 2);
        int tl = (lane & 3) * 8;
        s16x8 v = *(const s16x8*)&tb[dd * 40 + tl];
        *(s16x8*)(vp + (size_t)dd * T_DIM + tg0 + tl) = v;
      }
      asm volatile("s_waitcnt lgkmcnt(0)" ::: "memory");  // WAR before next bb
    }
  } else {
    // Q/K blocks: [t][d] scatter (32B runs across row16 lanes)
    for (int mi = 0; mi < 8; ++mi)
      for (int ni = 0; ni < 4; ++ni)
        for (int r = 0; r < 4; ++r) {
          int m = m0 + wm + mi * 16 + quad * 4 + r;
          int n = n0 + wn + ni * 16 + row16;
          int t = m >> 2, bb = m & 3;
          int which = n >> 10, hh = (n >> 6) & 15, dd = n & 63;
          Cq[(size_t)(which * 64 + bb * 16 + hh) * PLANE + (size_t)t * 64 + dd] =
              f2bf(acc[mi][ni][r]);
        }
  }
}

// ---------------------------------------------------------------------------
// gemm128 (m97 structure, swizzled LDS), fp32 output — out-proj.
// ---------------------------------------------------------------------------
__global__ __launch_bounds__(256)
void gemm128(const unsigned short* __restrict__ A,
             const unsigned short* __restrict__ Bw,
             float* __restrict__ Cf, int N, int K) {
  __shared__ __attribute__((aligned(16))) unsigned short As[128 * 64];
  __shared__ __attribute__((aligned(16))) unsigned short Bs[128 * 64];

  const int tid = threadIdx.x, lane = tid & 63, w = tid >> 6;
  const int row16 = lane & 15, quad = lane >> 4;
  const int m0 = blockIdx.y * 128, n0 = blockIdx.x * 128;
  const int wm = (w & 1) * 64, wn = (w >> 1) * 64;
  const int srow = lane >> 3;
  const int jsw = (lane & 7) ^ srow;
  const int sw7 = row16 & 7;

  f32x4 acc[4][4];
  for (int i = 0; i < 4; ++i)
    for (int j = 0; j < 4; ++j) acc[i][j] = (f32x4){0.f, 0.f, 0.f, 0.f};

  for (int k0 = 0; k0 < K; k0 += 64) {
    for (int i = 0; i < 4; ++i) {
      int ia = i * 4 + w;
      int r = ia * 8 + srow;
      gl2lds16(A  + (size_t)(m0 + r) * K + k0 + jsw * 8, &As[ia * 512]);
      gl2lds16(Bw + (size_t)(n0 + r) * K + k0 + jsw * 8, &Bs[ia * 512]);
    }
    __syncthreads();
    for (int kk = 0; kk < 2; ++kk) {
      s16x8 af[4], bfr[4];
      for (int mi = 0; mi < 4; ++mi)
        af[mi] = *(const s16x8*)&As[(wm + mi * 16 + row16) * 64 +
                                    (((kk * 4 + quad) ^ sw7) * 8)];
      for (int ni = 0; ni < 4; ++ni)
        bfr[ni] = *(const s16x8*)&Bs[(wn + ni * 16 + row16) * 64 +
                                     (((kk * 4 + quad) ^ sw7) * 8)];
      for (int mi = 0; mi < 4; ++mi)
        for (int ni = 0; ni < 4; ++ni)
          acc[mi][ni] = mfma16(af[mi], bfr[ni], acc[mi][ni]);
    }
    __syncthreads();
  }

  for (int mi = 0; mi < 4; ++mi)
    for (int ni = 0; ni < 4; ++ni)
      for (int r = 0; r < 4; ++r) {
        int m = m0 + wm + mi * 16 + quad * 4 + r;
        int n = n0 + wn + ni * 16 + row16;
        Cf[(size_t)m * N + n] = acc[mi][ni][r];
      }
}

// ---------------------------------------------------------------------------
// Flash attention. grid = (64, 8): bh = blockIdx.x, p = blockIdx.y.
// Linear id = p*64+bh -> id%8 = bh%8: all 8 q-tile-blocks of a bh land on
// the same XCD (K/V L2 locality; round-10: FETCH 110->30 MB). Block handles
// q-tiles 15-p then p (uniform 36 chunk-iters total). K/V staged 2-deep via
// DMA (48KB LDS -> 3 blocks/CU); counted vmcnt mid-loop, two raw s_barriers
// per iter (post-compute barrier clears the WAR before re-staging a buffer).
// W_q carries 0.125*log2e, so P = exp2(S) with no per-element scale mul.
// ---------------------------------------------------------------------------
__global__ __launch_bounds__(256)
void attn_fwd(const unsigned short* __restrict__ qkv,
              unsigned short* __restrict__ ctx) {
  __shared__ __attribute__((aligned(16))) unsigned short Ks[2][4096];
  __shared__ __attribute__((aligned(16))) unsigned short Vs[2][4096];
  __shared__ __attribute__((aligned(16))) unsigned short Ps[4][2048];

  const int tid = threadIdx.x, lane = tid & 63, w = tid >> 6;
  const int row16 = lane & 15, quad = lane >> 4;
  const int bh = blockIdx.x;     // 0..63
  const int p  = blockIdx.y;     // 0..7
  const int b = bh >> 4, h = bh & 15;

  const unsigned short* Qg = qkv + (size_t)bh * PLANE;          // [t][d]
  const unsigned short* Kg = qkv + (size_t)(64 + bh) * PLANE;   // [t][d]
  const unsigned short* Vt = qkv + (size_t)(128 + bh) * PLANE;  // [d][t]

  const int r8 = lane >> 3;
  const int jsw = (lane & 7) ^ r8;
  const int sw7 = row16 & 7;

  auto stage = [&](int c, int buf) {   // 4 DMA loads per wave per call
    for (int i2 = 0; i2 < 2; ++i2) {
      int i = w + i2 * 4;
      int r = i * 8 + r8;
      gl2lds16(Kg + (size_t)(c * 64 + r) * 64 + jsw * 8, &Ks[buf][i * 512]);
      gl2lds16(Vt + (size_t)r * T_DIM + c * 64 + jsw * 8, &Vs[buf][i * 512]);
    }
  };

  for (int half = 0; half < 2; ++half) {
    const int qt = half ? p : (15 - p);
    const int q0w = qt * 128 + w * 32;
    const int cmax = 2 * qt + 1;           // >= 1 always
    const int dc = 2 * qt + (w >> 1);

    s16x8 qb[2][2];
    for (int nq = 0; nq < 2; ++nq)
      for (int s = 0; s < 2; ++s)
        qb[nq][s] = *(const s16x8*)(Qg + (size_t)(q0w + nq * 16 + row16) * 64 +
                                    s * 32 + quad * 8);

    f32x4 O[4][2];
    for (int md = 0; md < 4; ++md)
      for (int nq = 0; nq < 2; ++nq) O[md][nq] = (f32x4){0.f, 0.f, 0.f, 0.f};
    float lp[2] = {0.f, 0.f};

    // 2-deep prologue (end-of-iter barrier of the previous half cleared WAR)
    stage(0, 0);
    stage(1, 1);

    for (int c = 0; c <= cmax; ++c) {
      const int buf = c & 1;
      // Counted wait: own group c landed; group c+1 stays in flight across
      // the barrier (T4 — drain to 0 only on the final iter).
      if (c < cmax) asm volatile("s_waitcnt vmcnt(4)" ::: "memory");
      else          asm volatile("s_waitcnt vmcnt(0)" ::: "memory");
      __builtin_amdgcn_s_barrier();  // all waves' group c landed

      if (c <= dc) {
        f32x4 S[4][2];
        for (int nt = 0; nt < 4; ++nt)
          for (int nq = 0; nq < 2; ++nq) S[nt][nq] = (f32x4){0.f, 0.f, 0.f, 0.f};
        __builtin_amdgcn_s_setprio(1);
        for (int nt = 0; nt < 4; ++nt)
          for (int s = 0; s < 2; ++s) {
            s16x8 ka = *(const s16x8*)&Ks[buf][(nt * 16 + row16) * 64 +
                                              (((s * 4 + quad) ^ sw7) * 8)];
            for (int nq = 0; nq < 2; ++nq)
              S[nt][nq] = mfma16(ka, qb[nq][s], S[nt][nq]);
          }
        __builtin_amdgcn_s_setprio(0);

        // softmax numerator + pack into Ps; diag path carries the causal mask
        auto softmax_store = [&](bool diagm) {
          for (int nq = 0; nq < 2; ++nq) {
            const int qg = q0w + nq * 16 + row16;
            for (int nt = 0; nt < 4; ++nt) {
              float pv[4];
              for (int r = 0; r < 4; ++r) {
                pv[r] = __builtin_amdgcn_exp2f(S[nt][nq][r]);
                if (diagm && (c * 64 + nt * 16 + quad * 4 + r) > qg) pv[r] = 0.f;
                lp[nq] += pv[r];
              }
              int qr = nq * 16 + row16;
              int pos = (nt * 2 + (quad >> 1)) ^ sw7;
              *(uint2*)&Ps[w][qr * 64 + pos * 8 + (quad & 1) * 4] =
                  make_uint2(packbf(pv[0], pv[1]), packbf(pv[2], pv[3]));
            }
          }
        };
        if (c == dc) softmax_store(true); else softmax_store(false);
        asm volatile("s_waitcnt lgkmcnt(0)" ::: "memory");  // Ps is per-wave

        __builtin_amdgcn_s_setprio(1);
        for (int sk = 0; sk < 2; ++sk) {
          s16x8 pb[2];
          for (int nq = 0; nq < 2; ++nq)
            pb[nq] = *(const s16x8*)&Ps[w][(nq * 16 + row16) * 64 +
                                           (((sk * 4 + quad) ^ sw7) * 8)];
          for (int md = 0; md < 4; ++md) {
            s16x8 va = *(const s16x8*)&Vs[buf][(md * 16 + row16) * 64 +
                                              (((sk * 4 + quad) ^ sw7) * 8)];
            for (int nq = 0; nq < 2; ++nq)
              O[md][nq] = mfma16(va, pb[nq], O[md][nq]);
          }
        }
        __builtin_amdgcn_s_setprio(0);
      }

      __builtin_amdgcn_s_barrier();  // all waves done reading buf -> WAR clear
      if (c + 2 <= cmax) stage(c + 2, buf);
    }

    for (int nq = 0; nq < 2; ++nq) {
      float s = lp[nq];
      s += __shfl_xor(s, 16);
      s += __shfl_xor(s, 32);
      float inv = 1.f / s;
      const int t = q0w + nq * 16 + row16;
      for (int md = 0; md < 4; ++md) {
        unsigned lo = packbf(O[md][nq][0] * inv, O[md][nq][1] * inv);
        unsigned hi = packbf(O[md][nq][2] * inv, O[md][nq][3] * inv);
        *(uint2*)&ctx[((size_t)t * B_DIM + b) * E_DIM + h * 64 + md * 16 +
                      quad * 4] = make_uint2(lo, hi);
      }
    }
  }
}

// ---------------------------------------------------------------------------
extern "C" void kernel_launch(void* const* d_in, const int* in_sizes, int n_in,
                              void* d_out, int out_size, void* d_ws,
                              size_t ws_size, hipStream_t stream) {
  const float* query = (const float*)d_in[0];  // [T,B,E] = [8192,1024]
  const float* win   = (const float*)d_in[1];  // [3072,1024]
  const float* wout  = (const float*)d_in[2];  // [1024,1024]
  float* out = (float*)d_out;

  const size_t qkv_el = (size_t)3 * 64 * PLANE;   // 25,165,824 ushort
  const size_t ctx_el = (size_t)T_DIM * B_DIM * E_DIM;  // 8,388,608 ushort

  unsigned short* qkvb = (unsigned short*)d_ws;
  unsigned short* ctxb = qkvb + qkv_el;
  unsigned short* xb   = ctxb;                   // dies before ctx written
  unsigned short* winb = (unsigned short*)d_out; // d_out scratch until gemm2

  // W_out bf16: fresh ws region after ctx when it fits (enables upfront
  // merged cvt); else reuse qkvb after attn (old path).
  const bool big_ws = ws_size >= (qkv_el + ctx_el + (size_t)E_DIM * E_DIM) * 2;
  unsigned short* woutb = big_ws ? (ctxb + ctx_el) : qkvb;

  // 0.125 (1/sqrt(D)) * log2(e): folded into W_q so attn uses exp2 directly.
  const float QSCALE = 0.18033688011112042f;

  cvt_all<<<big_ws ? 12288 : 11264, 256, 0, stream>>>(
      query, win, wout, xb, winb, woutb, QSCALE, big_ws ? 1 : 0);
  gemm256<<<dim3(3072 / 128, 8192 / 256), 256, 0, stream>>>(xb, winb, qkvb,
                                                            1024);
  attn_fwd<<<dim3(64, 8), 256, 0, stream>>>(qkvb, ctxb);
  if (!big_ws)
    cvt_bf16<<<1024, 256, 0, stream>>>(wout, woutb, (1024 * 1024) / 4);
  gemm128<<<dim3(8, 64), 256, 0, stream>>>(ctxb, woutb, out, 1024, 1024);
}

// Round 5
// 223.814 us; speedup vs baseline: 1.2453x; 1.0389x over previous
//
#include <hip/hip_runtime.h>

// ---------------------------------------------------------------------------
// SelfMultiheadAttn fwd: T=2048, B=4, E=1024, H=16, D=64, causal.
// Round 13 = round 12 resubmitted verbatim (round-12 bench died to an infra
// "container failed twice" error; kernel re-audited for deadlock/ledger bugs,
// none found).
//  * attn blocks 256 -> 512 threads (8 waves), same (64,8) grid. Round-11
//    lesson: grid caps residency at 2 blocks/CU, so add waves per block.
//    16 waves/CU (50% cap) vs 8. Each wave owns 16 q-rows (nq dim gone);
//    staging unchanged (each wave issues 1 K + 1 V DMA per chunk ->
//    vmcnt(2) mid-loop, vmcnt(0) final). dc = 2qt + (w>>2).
//    VGPR halves (S[4], O[4]); launch_bounds(512,4) keeps <=128.
// Kept: 2-deep K/V staging + counted vmcnt + two raw barriers/iter,
// uniform (15-p, p) pairing, same-bh-on-same-XCD grid (FETCH at 30MB =
// compulsory K/V floor), exp2-folded W_q scale, diag/non-diag softmax
// split, setprio around MFMA, DMA-only staging.
// ---------------------------------------------------------------------------

typedef float  f32x4  __attribute__((ext_vector_type(4)));
typedef short  s16x8  __attribute__((ext_vector_type(8)));
typedef __bf16 bf16x8 __attribute__((ext_vector_type(8)));

#define T_DIM 2048
#define B_DIM 4
#define E_DIM 1024
#define PLANE (T_DIM * 64)   // elements per (which,b,h) plane

__device__ inline unsigned short f2bf(float f) {
  return (unsigned short)((__builtin_bit_cast(unsigned int, f) + 0x8000u) >> 16);
}

__device__ inline f32x4 mfma16(s16x8 a, s16x8 b, f32x4 c) {
  return __builtin_amdgcn_mfma_f32_16x16x32_bf16(
      __builtin_bit_cast(bf16x8, a), __builtin_bit_cast(bf16x8, b), c, 0, 0, 0);
}

__device__ inline void gl2lds16(const unsigned short* g, unsigned short* l) {
  __builtin_amdgcn_global_load_lds(
      (__attribute__((address_space(1))) unsigned int*)g,
      (__attribute__((address_space(3))) unsigned int*)l, 16, 0, 0);
}

// pack hi16(a) | hi16(b)<<16  (bf16 truncation) in one v_perm
__device__ inline unsigned packbf(float a, float b) {
  return __builtin_amdgcn_perm(__builtin_bit_cast(unsigned, b),
                               __builtin_bit_cast(unsigned, a), 0x07060302u);
}

// ---------------------------------------------------------------------------
// Merged input conversion: blocks [0,8192) query -> xb; [8192,11264) W_in ->
// winb (first E*E/4 float4s carry the Q scale); [11264,12288) W_out -> wob
// (skipped when do_wout==0; fallback path converts W_out after attn).
// ---------------------------------------------------------------------------
__global__ __launch_bounds__(256)
void cvt_all(const float* __restrict__ q, const float* __restrict__ wi,
             const float* __restrict__ wo, unsigned short* __restrict__ xb,
             unsigned short* __restrict__ wib, unsigned short* __restrict__ wob,
             float qs, int do_wout) {
  int blk = blockIdx.x;
  const float* src;
  unsigned short* dst;
  int i;
  float sc = 1.0f;
  if (blk < 8192) {
    src = q; dst = xb; i = blk * 256 + threadIdx.x;
  } else if (blk < 11264) {
    src = wi; dst = wib; i = (blk - 8192) * 256 + threadIdx.x;
    if (i < (E_DIM * E_DIM / 4)) sc = qs;
  } else {
    if (!do_wout) return;
    src = wo; dst = wob; i = (blk - 11264) * 256 + threadIdx.x;
  }
  float4 v = ((const float4*)src)[i];
  ushort4 o;
  o.x = f2bf(v.x * sc); o.y = f2bf(v.y * sc);
  o.z = f2bf(v.z * sc); o.w = f2bf(v.w * sc);
  ((ushort4*)dst)[i] = o;
}

__global__ __launch_bounds__(256)
void cvt_bf16(const float* __restrict__ in, unsigned short* __restrict__ out,
              int n4) {
  int i = blockIdx.x * 256 + threadIdx.x;
  if (i >= n4) return;
  float4 v = ((const float4*)in)[i];
  ushort4 o;
  o.x = f2bf(v.x); o.y = f2bf(v.y); o.z = f2bf(v.z); o.w = f2bf(v.w);
  ((ushort4*)out)[i] = o;
}

// ---------------------------------------------------------------------------
// gemm256: C[m,n]=sum_k A[m,k]*B[n,k]; 256x128 tile; both operands DMA-staged
// into swizzled LDS (single-buffered, m97 structure). Epilogue -> qkv scatter,
// V block via per-wave LDS transpose (reuses As).
// ---------------------------------------------------------------------------
__global__ __launch_bounds__(256, 2)
void gemm256(const unsigned short* __restrict__ A,
             const unsigned short* __restrict__ Bw,
             unsigned short* __restrict__ Cq, int K) {
  __shared__ __attribute__((aligned(16))) unsigned short As[256 * 64];
  __shared__ __attribute__((aligned(16))) unsigned short Bs[128 * 64];

  const int tid = threadIdx.x, lane = tid & 63, w = tid >> 6;
  const int row16 = lane & 15, quad = lane >> 4;
  const int m0 = blockIdx.y * 256, n0 = blockIdx.x * 128;
  const int wm = (w & 1) * 128, wn = (w >> 1) * 64;
  const int srow = lane >> 3;                  // 0..7 row within issue
  const int jsw = (lane & 7) ^ srow;           // swizzled 16B-chunk (staging)
  const int sw7 = row16 & 7;                   // read-side swizzle key

  f32x4 acc[8][4];
  for (int i = 0; i < 8; ++i)
    for (int j = 0; j < 4; ++j) acc[i][j] = (f32x4){0.f, 0.f, 0.f, 0.f};

  for (int k0 = 0; k0 < K; k0 += 64) {
    for (int i2 = 0; i2 < 8; ++i2) {          // A: 32 issues, 8 per wave
      int ia = w * 8 + i2;
      int r = ia * 8 + srow;
      gl2lds16(A + (size_t)(m0 + r) * K + k0 + jsw * 8, &As[ia * 512]);
    }
    for (int i2 = 0; i2 < 4; ++i2) {          // B: 16 issues, 4 per wave
      int ib = w * 4 + i2;
      int r = ib * 8 + srow;
      gl2lds16(Bw + (size_t)(n0 + r) * K + k0 + jsw * 8, &Bs[ib * 512]);
    }
    __syncthreads();
    for (int kk = 0; kk < 2; ++kk) {
      s16x8 af[8], bfr[4];
      for (int mi = 0; mi < 8; ++mi)
        af[mi] = *(const s16x8*)&As[(wm + mi * 16 + row16) * 64 +
                                    (((kk * 4 + quad) ^ sw7) * 8)];
      for (int ni = 0; ni < 4; ++ni)
        bfr[ni] = *(const s16x8*)&Bs[(wn + ni * 16 + row16) * 64 +
                                     (((kk * 4 + quad) ^ sw7) * 8)];
      for (int mi = 0; mi < 8; ++mi)
        for (int ni = 0; ni < 4; ++ni)
          acc[mi][ni] = mfma16(af[mi], bfr[ni], acc[mi][ni]);
    }
    __syncthreads();
  }

  if (n0 >= 2048) {
    // V block: per-wave transpose in LDS (As free after final barrier).
    // t = tg0 + mi*4+quad ; b = reg r ; dd = ni*16+row16 ; head hw.
    const int hw = ((n0 & 1023) >> 6) + (w >> 1);
    const int tg0 = (m0 >> 2) + (w & 1) * 32;
    unsigned short* tb = &As[w * 2560];        // 64 dd x 32 tl, stride 40
    for (int bb = 0; bb < 4; ++bb) {
      for (int mi = 0; mi < 8; ++mi)
        for (int ni = 0; ni < 4; ++ni)
          tb[(ni * 16 + row16) * 40 + mi * 4 + quad] = f2bf(acc[mi][ni][bb]);
      asm volatile("s_waitcnt lgkmcnt(0)" ::: "memory");
      unsigned short* vp = Cq + (size_t)(128 + bb * 16 + hw) * PLANE;
      for (int it = 0; it < 4; ++it) {
        int dd = it * 16 + (lane >> 2);
        int tl = (lane & 3) * 8;
        s16x8 v = *(const s16x8*)&tb[dd * 40 + tl];
        *(s16x8*)(vp + (size_t)dd * T_DIM + tg0 + tl) = v;
      }
      asm volatile("s_waitcnt lgkmcnt(0)" ::: "memory");  // WAR before next bb
    }
  } else {
    // Q/K blocks: [t][d] scatter (32B runs across row16 lanes)
    for (int mi = 0; mi < 8; ++mi)
      for (int ni = 0; ni < 4; ++ni)
        for (int r = 0; r < 4; ++r) {
          int m = m0 + wm + mi * 16 + quad * 4 + r;
          int n = n0 + wn + ni * 16 + row16;
          int t = m >> 2, bb = m & 3;
          int which = n >> 10, hh = (n >> 6) & 15, dd = n & 63;
          Cq[(size_t)(which * 64 + bb * 16 + hh) * PLANE + (size_t)t * 64 + dd] =
              f2bf(acc[mi][ni][r]);
        }
  }
}

// ---------------------------------------------------------------------------
// gemm128 (m97 structure, swizzled LDS), fp32 output — out-proj.
// ---------------------------------------------------------------------------
__global__ __launch_bounds__(256)
void gemm128(const unsigned short* __restrict__ A,
             const unsigned short* __restrict__ Bw,
             float* __restrict__ Cf, int N, int K) {
  __shared__ __attribute__((aligned(16))) unsigned short As[128 * 64];
  __shared__ __attribute__((aligned(16))) unsigned short Bs[128 * 64];

  const int tid = threadIdx.x, lane = tid & 63, w = tid >> 6;
  const int row16 = lane & 15, quad = lane >> 4;
  const int m0 = blockIdx.y * 128, n0 = blockIdx.x * 128;
  const int wm = (w & 1) * 64, wn = (w >> 1) * 64;
  const int srow = lane >> 3;
  const int jsw = (lane & 7) ^ srow;
  const int sw7 = row16 & 7;

  f32x4 acc[4][4];
  for (int i = 0; i < 4; ++i)
    for (int j = 0; j < 4; ++j) acc[i][j] = (f32x4){0.f, 0.f, 0.f, 0.f};

  for (int k0 = 0; k0 < K; k0 += 64) {
    for (int i = 0; i < 4; ++i) {
      int ia = i * 4 + w;
      int r = ia * 8 + srow;
      gl2lds16(A  + (size_t)(m0 + r) * K + k0 + jsw * 8, &As[ia * 512]);
      gl2lds16(Bw + (size_t)(n0 + r) * K + k0 + jsw * 8, &Bs[ia * 512]);
    }
    __syncthreads();
    for (int kk = 0; kk < 2; ++kk) {
      s16x8 af[4], bfr[4];
      for (int mi = 0; mi < 4; ++mi)
        af[mi] = *(const s16x8*)&As[(wm + mi * 16 + row16) * 64 +
                                    (((kk * 4 + quad) ^ sw7) * 8)];
      for (int ni = 0; ni < 4; ++ni)
        bfr[ni] = *(const s16x8*)&Bs[(wn + ni * 16 + row16) * 64 +
                                     (((kk * 4 + quad) ^ sw7) * 8)];
      for (int mi = 0; mi < 4; ++mi)
        for (int ni = 0; ni < 4; ++ni)
          acc[mi][ni] = mfma16(af[mi], bfr[ni], acc[mi][ni]);
    }
    __syncthreads();
  }

  for (int mi = 0; mi < 4; ++mi)
    for (int ni = 0; ni < 4; ++ni)
      for (int r = 0; r < 4; ++r) {
        int m = m0 + wm + mi * 16 + quad * 4 + r;
        int n = n0 + wn + ni * 16 + row16;
        Cf[(size_t)m * N + n] = acc[mi][ni][r];
      }
}

// ---------------------------------------------------------------------------
// Flash attention. grid = (64, 8), 512 threads (8 waves). bh = blockIdx.x,
// p = blockIdx.y; linear id % 8 = bh % 8 -> same-bh blocks on same XCD.
// Block handles q-tiles 15-p then p (uniform 36 chunk-iters). Each wave owns
// 16 q-rows: q0w = qt*128 + w*16; waves 0-3 cover kv-diag chunk 2qt, waves
// 4-7 chunk 2qt+1 (dc = 2qt + (w>>2)). K/V staged 2-deep via DMA (48KB LDS);
// each wave issues 1 K + 1 V DMA per chunk -> counted vmcnt(2) mid-loop,
// vmcnt(0) final; two raw s_barriers per iter (WAR before re-staging).
// W_q carries 0.125*log2e, so P = exp2(S) with no per-element scale mul.
// ---------------------------------------------------------------------------
__global__ __launch_bounds__(512, 4)
void attn_fwd(const unsigned short* __restrict__ qkv,
              unsigned short* __restrict__ ctx) {
  __shared__ __attribute__((aligned(16))) unsigned short Ks[2][4096];
  __shared__ __attribute__((aligned(16))) unsigned short Vs[2][4096];
  __shared__ __attribute__((aligned(16))) unsigned short Ps[8][1024];

  const int tid = threadIdx.x, lane = tid & 63, w = tid >> 6;  // w 0..7
  const int row16 = lane & 15, quad = lane >> 4;
  const int bh = blockIdx.x;     // 0..63
  const int p  = blockIdx.y;     // 0..7
  const int b = bh >> 4, h = bh & 15;

  const unsigned short* Qg = qkv + (size_t)bh * PLANE;          // [t][d]
  const unsigned short* Kg = qkv + (size_t)(64 + bh) * PLANE;   // [t][d]
  const unsigned short* Vt = qkv + (size_t)(128 + bh) * PLANE;  // [d][t]

  const int r8 = lane >> 3;
  const int jsw = (lane & 7) ^ r8;
  const int sw7 = row16 & 7;

  auto stage = [&](int c, int buf) {   // 2 DMA issues per wave per call
    int r = w * 8 + r8;                // 8 waves cover all 64 rows
    gl2lds16(Kg + (size_t)(c * 64 + r) * 64 + jsw * 8, &Ks[buf][w * 512]);
    gl2lds16(Vt + (size_t)r * T_DIM + c * 64 + jsw * 8, &Vs[buf][w * 512]);
  };

  for (int half = 0; half < 2; ++half) {
    const int qt = half ? p : (15 - p);
    const int q0w = qt * 128 + w * 16;
    const int cmax = 2 * qt + 1;           // >= 1 always
    const int dc = 2 * qt + (w >> 2);

    s16x8 qb[2];
    for (int s = 0; s < 2; ++s)
      qb[s] = *(const s16x8*)(Qg + (size_t)(q0w + row16) * 64 + s * 32 +
                              quad * 8);

    f32x4 O[4];
    for (int md = 0; md < 4; ++md) O[md] = (f32x4){0.f, 0.f, 0.f, 0.f};
    float lp = 0.f;

    // 2-deep prologue (final end-of-iter barrier of prev half cleared WAR)
    stage(0, 0);
    stage(1, 1);

    for (int c = 0; c <= cmax; ++c) {
      const int buf = c & 1;
      // Counted wait: own chunk c landed; chunk c+1 stays in flight across
      // the barrier (T4 — drain to 0 only on the final iter).
      if (c < cmax) asm volatile("s_waitcnt vmcnt(2)" ::: "memory");
      else          asm volatile("s_waitcnt vmcnt(0)" ::: "memory");
      __builtin_amdgcn_s_barrier();  // all waves' chunk c landed

      if (c <= dc) {
        f32x4 S[4];
        for (int nt = 0; nt < 4; ++nt) S[nt] = (f32x4){0.f, 0.f, 0.f, 0.f};
        __builtin_amdgcn_s_setprio(1);
        for (int nt = 0; nt < 4; ++nt)
          for (int s = 0; s < 2; ++s) {
            s16x8 ka = *(const s16x8*)&Ks[buf][(nt * 16 + row16) * 64 +
                                              (((s * 4 + quad) ^ sw7) * 8)];
            S[nt] = mfma16(ka, qb[s], S[nt]);
          }
        __builtin_amdgcn_s_setprio(0);

        // softmax numerator + pack into Ps; diag path carries the causal mask
        const int qg = q0w + row16;
        auto softmax_store = [&](bool diagm) {
          for (int nt = 0; nt < 4; ++nt) {
            float pv[4];
            for (int r = 0; r < 4; ++r) {
              pv[r] = __builtin_amdgcn_exp2f(S[nt][r]);
              if (diagm && (c * 64 + nt * 16 + quad * 4 + r) > qg) pv[r] = 0.f;
              lp += pv[r];
            }
            int pos = (nt * 2 + (quad >> 1)) ^ sw7;
            *(uint2*)&Ps[w][row16 * 64 + pos * 8 + (quad & 1) * 4] =
                make_uint2(packbf(pv[0], pv[1]), packbf(pv[2], pv[3]));
          }
        };
        if (c == dc) softmax_store(true); else softmax_store(false);
        asm volatile("s_waitcnt lgkmcnt(0)" ::: "memory");  // Ps is per-wave

        __builtin_amdgcn_s_setprio(1);
        for (int sk = 0; sk < 2; ++sk) {
          s16x8 pb = *(const s16x8*)&Ps[w][row16 * 64 +
                                          (((sk * 4 + quad) ^ sw7) * 8)];
          for (int md = 0; md < 4; ++md) {
            s16x8 va = *(const s16x8*)&Vs[buf][(md * 16 + row16) * 64 +
                                              (((sk * 4 + quad) ^ sw7) * 8)];
            O[md] = mfma16(va, pb, O[md]);
          }
        }
        __builtin_amdgcn_s_setprio(0);
      }

      __builtin_amdgcn_s_barrier();  // all waves done reading buf -> WAR clear
      if (c + 2 <= cmax) stage(c + 2, buf);
    }

    {
      float s = lp;
      s += __shfl_xor(s, 16);
      s += __shfl_xor(s, 32);
      float inv = 1.f / s;
      const int t = q0w + row16;
      for (int md = 0; md < 4; ++md) {
        unsigned lo = packbf(O[md][0] * inv, O[md][1] * inv);
        unsigned hi = packbf(O[md][2] * inv, O[md][3] * inv);
        *(uint2*)&ctx[((size_t)t * B_DIM + b) * E_DIM + h * 64 + md * 16 +
                      quad * 4] = make_uint2(lo, hi);
      }
    }
  }
}

// ---------------------------------------------------------------------------
extern "C" void kernel_launch(void* const* d_in, const int* in_sizes, int n_in,
                              void* d_out, int out_size, void* d_ws,
                              size_t ws_size, hipStream_t stream) {
  const float* query = (const float*)d_in[0];  // [T,B,E] = [8192,1024]
  const float* win   = (const float*)d_in[1];  // [3072,1024]
  const float* wout  = (const float*)d_in[2];  // [1024,1024]
  float* out = (float*)d_out;

  const size_t qkv_el = (size_t)3 * 64 * PLANE;   // 25,165,824 ushort
  const size_t ctx_el = (size_t)T_DIM * B_DIM * E_DIM;  // 8,388,608 ushort

  unsigned short* qkvb = (unsigned short*)d_ws;
  unsigned short* ctxb = qkvb + qkv_el;
  unsigned short* xb   = ctxb;                   // dies before ctx written
  unsigned short* winb = (unsigned short*)d_out; // d_out scratch until gemm2

  // W_out bf16: fresh ws region after ctx when it fits (enables upfront
  // merged cvt); else reuse qkvb after attn (old path).
  const bool big_ws = ws_size >= (qkv_el + ctx_el + (size_t)E_DIM * E_DIM) * 2;
  unsigned short* woutb = big_ws ? (ctxb + ctx_el) : qkvb;

  // 0.125 (1/sqrt(D)) * log2(e): folded into W_q so attn uses exp2 directly.
  const float QSCALE = 0.18033688011112042f;

  cvt_all<<<big_ws ? 12288 : 11264, 256, 0, stream>>>(
      query, win, wout, xb, winb, woutb, QSCALE, big_ws ? 1 : 0);
  gemm256<<<dim3(3072 / 128, 8192 / 256), 256, 0, stream>>>(xb, winb, qkvb,
                                                            1024);
  attn_fwd<<<dim3(64, 8), 512, 0, stream>>>(qkvb, ctxb);
  if (!big_ws)
    cvt_bf16<<<1024, 256, 0, stream>>>(wout, woutb, (1024 * 1024) / 4);
  gemm128<<<dim3(8, 64), 256, 0, stream>>>(ctxb, woutb, out, 1024, 1024);
}